// Round 2
// baseline (202.054 us; speedup 1.0000x reference)
//
#include <hip/hip_runtime.h>
#include <hip/hip_bf16.h>
#include <math.h>

typedef __attribute__((ext_vector_type(8))) short short8;
typedef __attribute__((ext_vector_type(4))) float floatx4;

static __device__ __forceinline__ unsigned short f2bf(float f) {
    union { float f; unsigned int u; } a; a.f = f;
    unsigned int u = a.u;
    return (unsigned short)((u + 0x7FFFu + ((u >> 16) & 1u)) >> 16);
}
static __device__ __forceinline__ float bf2f(unsigned short h) {
    union { unsigned int u; float f; } a; a.u = ((unsigned int)h) << 16;
    return a.f;
}

// ---------------- fp32 -> bf16 convert, 8 elems/thread ----------------
static __device__ __forceinline__ void cvt8(const float* __restrict__ src,
                                            unsigned short* __restrict__ dst, int i) {
    float4 v0 = *(const float4*)(src + i);
    float4 v1 = *(const float4*)(src + i + 4);
    ushort4 o0, o1;
    o0.x = f2bf(v0.x); o0.y = f2bf(v0.y); o0.z = f2bf(v0.z); o0.w = f2bf(v0.w);
    o1.x = f2bf(v1.x); o1.y = f2bf(v1.y); o1.z = f2bf(v1.z); o1.w = f2bf(v1.w);
    *(ushort4*)(dst + i) = o0;
    *(ushort4*)(dst + i + 4) = o1;
}

// One launch: x (2048 blks) + Wq/Wk/Wv (512 blks each) + l zero (1 blk).
struct CV { const float* x; unsigned short* xb;
            const float* W[3]; unsigned short* Wb[3]; float* l; };
__global__ __launch_bounds__(256)
void cvt_all(CV a) {
    int b = blockIdx.x, t = threadIdx.x;
    if (b < 2048) {
        cvt8(a.x, a.xb, (b * 256 + t) * 8);
    } else if (b < 3584) {
        int z  = (b - 2048) >> 9;
        int bb = (b - 2048) & 511;
        cvt8(a.W[z], a.Wb[z], (bb * 256 + t) * 8);
    } else {
        float4 zz = {0.f, 0.f, 0.f, 0.f};
        #pragma unroll
        for (int c = 0; c < 4; c++)
            *(float4*)(a.l + t * 16 + c * 4) = zz;
    }
}

// inline-asm ds_read_b128: invisible to the compiler's waitcnt pass, so no
// vmcnt(0) drains get injected to order these vs in-flight global_load_lds.
// Ordering is provided manually: lgkmcnt(0)+sched_barrier(0) before MFMA
// (rule #18), barriers for cross-wave, vmcnt(6) checkpoints for staging RAW.
#define DSR(dst, base, OFF)                                                    \
    asm volatile("ds_read_b128 %0, %1 offset:%2"                               \
                 : "=v"(dst) : "v"(base), "n"(OFF))

typedef __attribute__((address_space(3))) char* lds3p;

// ============================================================================
// 256x256 8-phase GEMM core (C += A B^T, K = 1024 = 16 tiles of BK=64)
//
// 512 threads = 8 waves (2M x 4N); per-wave output 128x64 (acc[8][4]).
// LDS 128 KiB: A/B x dbuf x (2 K-half units of 256 rows x 32 cols = 16 KB).
// Per K-tile: 4 phases (ih = M-half, ks = K-half), 16 MFMA each.
// Stage schedule (verified hazard-free, r1):
//   s4=0: A-kh1(t+1)   s4=1: B-kh0(t+2)   s4=2: A-kh0(t+2)   s4=3: B-kh1(t+2)
// vmcnt(6) checkpoints only at phases 4/8 (2 insts/unit, 3 units in flight).
// Prologue: 7 units, then vmcnt(6)+barrier.
// Raw s_barrier (never __syncthreads) -> no compiler vmcnt(0) drains in-loop.
// LDS chunk swizzle: slot ch holds global chunk ch ^ ((row>>1)&3); source
// pre-swizzled, read applies same XOR (bank conflicts measured negligible).
// Fragment reads are inline-asm ds_read_b128 with ALL phase/frag strides as
// offset: immediates (base pointers loop-invariant -> zero per-phase addr VALU).
// ============================================================================
__device__ __forceinline__ void gemm256_core(
    const unsigned short* __restrict__ A, const unsigned short* __restrict__ B,
    int lda, int k_begin, int bm, int bn,
    unsigned short* lds, floatx4 (&acc)[8][4])
{
    const int t    = threadIdx.x;
    const int wave = t >> 6;
    const int lane = t & 63;
    const int wrow = wave >> 2;        // 0..1
    const int wcol = wave & 3;         // 0..3
    const int lm   = lane & 15;
    const int ce8  = (((lane >> 4) ^ ((lm >> 1) & 3)) << 3);   // swizzled chunk (elems)

    // staging: thread t owns rows t>>2 and t>>2 + 128 of the unit
    const int srow = t >> 2;
    const int gsh  = (((t & 3) ^ ((srow >> 1) & 3)) << 3);     // pre-swizzled src chunk
    const unsigned short* srcA = A + (size_t)(bm + srow) * lda + k_begin + gsh;
    const unsigned short* srcB = B + (size_t)(bn + srow) * lda + k_begin + gsh;
    const size_t rstep = (size_t)128 * lda;
    char* ldsc = (char*)lds;
    const int w1k = wave << 10;

    // loop-invariant ds_read base pointers (as3, 32-bit): dbuf/kh/frag strides
    // all go into offset immediates (A max 56320, B max 52224 -> < 65536).
    lds3p lp3 = (lds3p)lds;
    lds3p va = lp3 + (((wrow << 7) + lm) * 64 + (ce8 << 1));           // A region
    lds3p vb = lp3 + (65536 + ((wcol << 6) + lm) * 64 + (ce8 << 1));   // B region

#define STAGE(kind, kh, tau) do {                                              \
        int taue_ = (tau) >= 16 ? (tau) - 2 : (tau);  /* dummy keeps vmcnt uniform */ \
        int ko_ = (taue_ << 6) + ((kh) << 5);                                  \
        unsigned lo_ = ((kind) << 16) + (((tau) & 1) << 15) + ((kh) << 14) + w1k; \
        const unsigned short* s_ = ((kind) ? srcB : srcA) + ko_;               \
        __builtin_amdgcn_global_load_lds(                                      \
            (const __attribute__((address_space(1))) void*)s_,                 \
            (__attribute__((address_space(3))) void*)(ldsc + lo_), 16, 0, 0);  \
        __builtin_amdgcn_global_load_lds(                                      \
            (const __attribute__((address_space(1))) void*)(s_ + rstep),       \
            (__attribute__((address_space(3))) void*)(ldsc + lo_ + 8192), 16, 0, 0); \
    } while (0)

    // prologue: tile0 {B0,A0,B1,A1} + tile1 {B0,A0,B1}
    STAGE(1, 0, 0); STAGE(0, 0, 0); STAGE(1, 1, 0); STAGE(0, 1, 0);
    STAGE(1, 0, 1); STAGE(0, 0, 1); STAGE(1, 1, 1);
    asm volatile("s_waitcnt vmcnt(6)" ::: "memory");
    __builtin_amdgcn_s_barrier();

    short8 b4[4];
    for (int t2 = 0; t2 < 16; t2 += 2) {
        #pragma unroll
        for (int s = 0; s < 8; s++) {
            const int hi = s >> 2;          // tile parity within pair (t2 even)
            const int s4 = s & 3;
            const int ks = s4 >> 1, ih = s4 & 1;
            const int tc = t2 + hi;
            constexpr int DB = 32768, KH = 16384, FR = 1024;
            const int PB = hi * DB + ks * KH;   // compile-time per unrolled s
            short8 na[4];
            DSR(na[0], va, PB + (ih * 4 + 0) * FR);
            DSR(na[1], va, PB + (ih * 4 + 1) * FR);
            DSR(na[2], va, PB + (ih * 4 + 2) * FR);
            DSR(na[3], va, PB + (ih * 4 + 3) * FR);
            if (s4 == 0 || s4 == 2) {
                DSR(b4[0], vb, PB + 0 * FR);
                DSR(b4[1], vb, PB + 1 * FR);
                DSR(b4[2], vb, PB + 2 * FR);
                DSR(b4[3], vb, PB + 3 * FR);
            }
            __builtin_amdgcn_sched_barrier(0);   // reads issue before STAGE
            if      (s4 == 0) STAGE(0, 1, tc + 1);
            else if (s4 == 1) STAGE(1, 0, tc + 2);
            else if (s4 == 2) STAGE(0, 0, tc + 2);
            else              STAGE(1, 1, tc + 2);
            __builtin_amdgcn_s_barrier();
            asm volatile("s_waitcnt lgkmcnt(0)" ::: "memory");
            __builtin_amdgcn_sched_barrier(0);   // rule #18: MFMA must not hoist
            __builtin_amdgcn_s_setprio(1);
            #pragma unroll
            for (int ii = 0; ii < 4; ii++)
                #pragma unroll
                for (int j = 0; j < 4; j++)
                    acc[ih * 4 + ii][j] = __builtin_amdgcn_mfma_f32_16x16x32_bf16(
                        na[ii], b4[j], acc[ih * 4 + ii][j], 0, 0, 0);
            __builtin_amdgcn_s_setprio(0);
            if (s4 == 3) asm volatile("s_waitcnt vmcnt(6)" ::: "memory");
            __builtin_amdgcn_s_barrier();
        }
    }
#undef STAGE
}

// ---- 256x256 tile store via LDS (two 128-row passes, stride 264) -----------
// Scattered 2B epilogue stores trigger L2 write-allocate HBM fetches; staging
// in LDS then streaming full 256B-per-row lines avoids it (verified lineage).
// First __syncthreads drains the in-flight dummy global_load_lds (full drain).
__device__ __forceinline__ void tile_store256(unsigned short* sm, // >= 128*264
                                              floatx4 (&acc)[8][4], float scale, int trans,
                                              unsigned short* __restrict__ C, int ldc,
                                              int rbase, int cbase)
{
    const int t = threadIdx.x, wave = t >> 6, lane = t & 63;
    const int wrow = wave >> 2, wcol = wave & 3;
    const int lm = lane & 15, rq = ((lane >> 4) << 2);
    #pragma unroll
    for (int h = 0; h < 2; h++) {
        __syncthreads();
        if (!trans) {
            if (wrow == h) {
                #pragma unroll
                for (int i = 0; i < 8; i++)
                    #pragma unroll
                    for (int j = 0; j < 4; j++)
                        #pragma unroll
                        for (int r = 0; r < 4; r++)
                            sm[(i * 16 + rq + r) * 264 + wcol * 64 + j * 16 + lm] =
                                f2bf(acc[i][j][r] * scale);
            }
        } else {
            if ((wcol >> 1) == h) {
                #pragma unroll
                for (int i = 0; i < 8; i++)
                    #pragma unroll
                    for (int j = 0; j < 4; j++) {
                        ushort4 v;
                        v.x = f2bf(acc[i][j][0] * scale);
                        v.y = f2bf(acc[i][j][1] * scale);
                        v.z = f2bf(acc[i][j][2] * scale);
                        v.w = f2bf(acc[i][j][3] * scale);
                        *(ushort4*)&sm[((wcol & 1) * 64 + j * 16 + lm) * 264 +
                                       wrow * 128 + i * 16 + rq] = v;
                    }
            }
        }
        __syncthreads();
        #pragma unroll
        for (int p = 0; p < 4; p++) {
            int row = p * 32 + (t >> 4);
            int c0  = (t & 15) * 8;
            *(short8*)&C[(size_t)(rbase + h * 128 + row) * ldc + cbase + c0] =
                *(const short8*)&sm[row * 264 + c0];
            *(short8*)&C[(size_t)(rbase + h * 128 + row) * ldc + cbase + c0 + 128] =
                *(const short8*)&sm[row * 264 + c0 + 128];
        }
    }
}

// ---- fused 3-way projection: {Wq->q(*1/32), Wk->k, Wv->vT} ----------------
struct P3 { const unsigned short* W[3]; unsigned short* O[3]; };
__global__ __launch_bounds__(512, 2)
void proj3(const unsigned short* __restrict__ xb, P3 a) {
    __shared__ __align__(16) unsigned short lds[65536];
    const int lid = blockIdx.x;                 // 0..191
    const int xcd = lid & 7, rem = lid >> 3;
    const int z   = rem >> 3;                   // 0..2
    const int idx = xcd * 8 + (rem & 7);        // 0..63
    const int by = idx >> 2, bx = idx & 3;      // 16 x 4 tiles of 256
    const int bm = by * 256, bn = bx * 256;

    floatx4 acc[8][4];
    #pragma unroll
    for (int i = 0; i < 8; i++)
        #pragma unroll
        for (int j = 0; j < 4; j++) { floatx4 zz = {0.f,0.f,0.f,0.f}; acc[i][j] = zz; }

    gemm256_core(xb, a.W[z], 1024, 0, bm, bn, lds, acc);

    const int trans = (z == 2);
    const float scale = (z == 0) ? 0.03125f : 1.0f;
    tile_store256(lds, acc, scale, trans, a.O[z],
                  trans ? 4096 : 1024, trans ? bn : bm, trans ? bm : bn);
}

// ---- PS-GEMM: P = exp(q k^T) bf16 (scale pre-folded into q), row sums -> l -
__global__ __launch_bounds__(512, 2)
void gemm_ps(const unsigned short* __restrict__ q, const unsigned short* __restrict__ k,
             unsigned short* __restrict__ Pm, float* __restrict__ l) {
    __shared__ __align__(16) unsigned short lds[65536];
    const int lid = blockIdx.x;                 // 0..255 (exactly 1 block/CU)
    const int xcd = lid & 7, r32 = lid >> 3;
    const int by = ((xcd >> 1) << 2) + (r32 & 3);
    const int bx = ((xcd & 1) << 3) + (r32 >> 2);
    const int bm = by * 256, bn = bx * 256;

    floatx4 acc[8][4];
    #pragma unroll
    for (int i = 0; i < 8; i++)
        #pragma unroll
        for (int j = 0; j < 4; j++) { floatx4 zz = {0.f,0.f,0.f,0.f}; acc[i][j] = zz; }

    gemm256_core(q, k, 1024, 0, bm, bn, lds, acc);

    const int lane = threadIdx.x & 63, wave = threadIdx.x >> 6;
    const int wrow = wave >> 2;
    const int lm = lane & 15, rq = ((lane >> 4) << 2);
    #pragma unroll
    for (int i = 0; i < 8; i++) {
        #pragma unroll
        for (int r = 0; r < 4; r++) {
            float rs = 0.f;
            #pragma unroll
            for (int j = 0; j < 4; j++) {
                float e = __expf(acc[i][j][r]);
                acc[i][j][r] = e;
                rs += e;
            }
            rs += __shfl_xor(rs, 1);
            rs += __shfl_xor(rs, 2);
            rs += __shfl_xor(rs, 4);
            rs += __shfl_xor(rs, 8);
            if (lm == 0) atomicAdd(l + bm + wrow * 128 + i * 16 + rq + r, rs);
        }
    }
    tile_store256(lds, acc, 1.0f, 0, Pm, 4096, bm, bn);
}

// ---- O-GEMM split-K=4: 256x256 tiles, bf16 partials ------------------------
__global__ __launch_bounds__(512, 2)
void gemm_osplit(const unsigned short* __restrict__ Pm, const unsigned short* __restrict__ vT,
                 unsigned short* __restrict__ Opart) {
    __shared__ __align__(16) unsigned short lds[65536];
    const int lid = blockIdx.x;                 // 0..255
    const int xcd = lid & 7, r32 = lid >> 3;
    const int z   = r32 & 3;                    // K quarter
    const int idx = (r32 >> 2) * 8 + xcd;       // 0..63
    const int by = idx >> 2, bx = idx & 3;      // 16 x 4 tiles

    floatx4 acc[8][4];
    #pragma unroll
    for (int i = 0; i < 8; i++)
        #pragma unroll
        for (int j = 0; j < 4; j++) { floatx4 zz = {0.f,0.f,0.f,0.f}; acc[i][j] = zz; }

    gemm256_core(Pm, vT, 4096, z * 1024, by * 256, bx * 256, lds, acc);

    tile_store256(lds, acc, 1.0f, 0, Opart + (size_t)z * (4096 * 1024), 1024,
                  by * 256, bx * 256);
}

// ---- reduce 4 bf16 split-K partials + apply deferred 1/l row scale ---------
__global__ __launch_bounds__(256)
void reduce_scale(const unsigned short* __restrict__ Op, const float* __restrict__ l,
                  float* __restrict__ out) {
    int i = (blockIdx.x * 256 + threadIdx.x) * 4;
    ushort4 a = *(const ushort4*)(Op + i);
    ushort4 b = *(const ushort4*)(Op + 4194304 + i);
    ushort4 c = *(const ushort4*)(Op + 8388608 + i);
    ushort4 d = *(const ushort4*)(Op + 12582912 + i);
    float inv = 1.0f / l[i >> 10];
    float4 o;
    o.x = (bf2f(a.x) + bf2f(b.x) + bf2f(c.x) + bf2f(d.x)) * inv;
    o.y = (bf2f(a.y) + bf2f(b.y) + bf2f(c.y) + bf2f(d.y)) * inv;
    o.z = (bf2f(a.z) + bf2f(b.z) + bf2f(c.z) + bf2f(d.z)) * inv;
    o.w = (bf2f(a.w) + bf2f(b.w) + bf2f(c.w) + bf2f(d.w)) * inv;
    *(float4*)(out + i) = o;
}

// ---------------- driver -----------------------------------------------
extern "C" void kernel_launch(void* const* d_in, const int* in_sizes, int n_in,
                              void* d_out, int out_size, void* d_ws, size_t ws_size,
                              hipStream_t stream) {
    const float* x  = (const float*)d_in[0];
    const float* Wq = (const float*)d_in[1];
    const float* Wk = (const float*)d_in[2];
    const float* Wv = (const float*)d_in[3];
    float* out = (float*)d_out;

    char* ws = (char*)d_ws;
    const size_t MB = 1u << 20;
    unsigned short* vTb = (unsigned short*)(ws);             //  0..8   bf16 [D x SEQ]
    unsigned short* xb  = (unsigned short*)(ws + 8 * MB);    //  8..16
    unsigned short* Wqb = (unsigned short*)(ws + 16 * MB);   // 16..18
    unsigned short* Wkb = (unsigned short*)(ws + 18 * MB);   // 18..20
    unsigned short* Wvb = (unsigned short*)(ws + 20 * MB);   // 20..22
    unsigned short* qb  = (unsigned short*)(ws + 22 * MB);   // 22..30
    unsigned short* kb  = (unsigned short*)(ws + 30 * MB);   // 30..38
    unsigned short* P   = (unsigned short*)(ws + 40 * MB);   // 40..72  bf16 [SEQ x SEQ]
    float*          l   = (float*)(ws + 72 * MB);            // 72..72.016 row sums
    // Opart aliases xb/W/qb/kb (all dead once gemm_ps has run): 4 x 8 MB
    unsigned short* Opart = (unsigned short*)(ws + 8 * MB);  //  8..40

    dim3 b256(256), b512(512);
    CV cv = {x, xb, {Wq, Wk, Wv}, {Wqb, Wkb, Wvb}, l};
    cvt_all<<<dim3(3585), b256, 0, stream>>>(cv);

    // q(*1/32)/k/vT: 256x256 tiles, 8-phase core, 192 blocks
    P3 p3 = {{Wqb, Wkb, Wvb}, {qb, kb, vTb}};
    proj3<<<dim3(192), b512, 0, stream>>>(xb, p3);

    // P = exp(q k^T) bf16 + row sums l (256 blocks = 1/CU)
    gemm_ps<<<dim3(256), b512, 0, stream>>>(qb, kb, P, l);

    // O partials bf16, split-K=4 (256 blocks)
    gemm_osplit<<<dim3(256), b512, 0, stream>>>(P, vTb, Opart);

    // out = (sum of 4 partials) / l[row]
    reduce_scale<<<dim3(4096), b256, 0, stream>>>(Opart, l, out);
}

// Round 3
// 195.946 us; speedup vs baseline: 1.0312x; 1.0312x over previous
//
#include <hip/hip_runtime.h>
#include <hip/hip_bf16.h>
#include <math.h>

typedef __attribute__((ext_vector_type(8))) short short8;
typedef __attribute__((ext_vector_type(4))) float floatx4;

static __device__ __forceinline__ unsigned short f2bf(float f) {
    union { float f; unsigned int u; } a; a.f = f;
    unsigned int u = a.u;
    return (unsigned short)((u + 0x7FFFu + ((u >> 16) & 1u)) >> 16);
}
static __device__ __forceinline__ float bf2f(unsigned short h) {
    union { unsigned int u; float f; } a; a.u = ((unsigned int)h) << 16;
    return a.f;
}

// ---------------- fp32 -> bf16 convert, 8 elems/thread ----------------
static __device__ __forceinline__ void cvt8(const float* __restrict__ src,
                                            unsigned short* __restrict__ dst, int i) {
    float4 v0 = *(const float4*)(src + i);
    float4 v1 = *(const float4*)(src + i + 4);
    ushort4 o0, o1;
    o0.x = f2bf(v0.x); o0.y = f2bf(v0.y); o0.z = f2bf(v0.z); o0.w = f2bf(v0.w);
    o1.x = f2bf(v1.x); o1.y = f2bf(v1.y); o1.z = f2bf(v1.z); o1.w = f2bf(v1.w);
    *(ushort4*)(dst + i) = o0;
    *(ushort4*)(dst + i + 4) = o1;
}

// One launch: x (2048 blks) + Wq/Wk/Wv (512 blks each) + l zero (1 blk).
struct CV { const float* x; unsigned short* xb;
            const float* W[3]; unsigned short* Wb[3]; float* l; };
__global__ __launch_bounds__(256)
void cvt_all(CV a) {
    int b = blockIdx.x, t = threadIdx.x;
    if (b < 2048) {
        cvt8(a.x, a.xb, (b * 256 + t) * 8);
    } else if (b < 3584) {
        int z  = (b - 2048) >> 9;
        int bb = (b - 2048) & 511;
        cvt8(a.W[z], a.Wb[z], (bb * 256 + t) * 8);
    } else {
        float4 zz = {0.f, 0.f, 0.f, 0.f};
        #pragma unroll
        for (int c = 0; c < 4; c++)
            *(float4*)(a.l + t * 16 + c * 4) = zz;
    }
}

// inline-asm ds_read_b128: invisible to the compiler's waitcnt pass (no
// injected vmcnt(0) drains vs in-flight global_load_lds). Ordering is manual:
// rolling counted lgkmcnt + sched_barrier(0) before each MFMA group (rule
// #18), raw s_barrier for cross-wave, vmcnt(6) checkpoints for staging RAW.
#define DSR(dst, base, OFF)                                                    \
    asm volatile("ds_read_b128 %0, %1 offset:%2"                               \
                 : "=v"(dst) : "v"(base), "n"(OFF))
#define LGKM(N) asm volatile("s_waitcnt lgkmcnt(" #N ")" ::: "memory")
#define SBAR()  asm volatile("s_barrier" ::: "memory")

typedef __attribute__((address_space(3))) char* lds3p;

// ============================================================================
// 256x256 GEMM core (C += A B^T, K = 1024 = 16 tiles of BK=64)
//
// 512 threads = 8 waves (2M x 4N); per-wave output 128x64 (acc[8][4]).
// LDS 128 KiB: A/B x dbuf x (2 K-half units of 256 rows x 32 cols = 16 KB).
// Per K-tile: 4 phases P(ks,ih) = (0,0),(0,1),(1,0),(1,1); 16 MFMA each.
// Stage schedule (hazard-free, r1; unchanged):
//   P0: A-kh1(t+1)   P1: B-kh0(t+2)   P2: A-kh0(t+2)   P3: B-kh1(t+2)
// vmcnt(6) checkpoints only at tile end (2 loads/unit, 3 units in flight).
// r3 changes (attack the read->MFMA serialization seen at 1886 cyc/phase):
//  - ONE barrier per phase (end only). WAR re-derived: reads complete before
//    own lgkmcnt(0) -> before end barrier; conflicting STAGE issues >=1
//    barrier later; same-parity slot overwrites are >=2 phases after reads.
//  - rolling counted lgkmcnt: issue [b4 x4, na x4], then lgkm(3)+4 MFMA,
//    lgkm(2)+4, lgkm(1)+4, lgkm(0)+4 -> LDS drain overlaps MFMA stream.
//  - raw asm s_barrier (no builtin) -> backend cannot attach vmcnt drains.
// ============================================================================
__device__ __forceinline__ void gemm256_core(
    const unsigned short* __restrict__ A, const unsigned short* __restrict__ B,
    int lda, int k_begin, int bm, int bn,
    unsigned short* lds, floatx4 (&acc)[8][4])
{
    const int t    = threadIdx.x;
    const int wave = t >> 6;
    const int lane = t & 63;
    const int wrow = wave >> 2;        // 0..1
    const int wcol = wave & 3;         // 0..3
    const int lm   = lane & 15;
    const int ce8  = (((lane >> 4) ^ ((lm >> 1) & 3)) << 3);   // swizzled chunk (elems)

    // staging: thread t owns rows t>>2 and t>>2 + 128 of the unit
    const int srow = t >> 2;
    const int gsh  = (((t & 3) ^ ((srow >> 1) & 3)) << 3);     // pre-swizzled src chunk
    const unsigned short* srcA = A + (size_t)(bm + srow) * lda + k_begin + gsh;
    const unsigned short* srcB = B + (size_t)(bn + srow) * lda + k_begin + gsh;
    const size_t rstep = (size_t)128 * lda;
    char* ldsc = (char*)lds;
    const int w1k = wave << 10;

    // loop-invariant ds_read base pointers (as3): dbuf/kh/frag strides all in
    // offset immediates (A max 56320, B max 52224 -> < 65536).
    lds3p lp3 = (lds3p)lds;
    lds3p va = lp3 + (((wrow << 7) + lm) * 64 + (ce8 << 1));           // A region
    lds3p vb = lp3 + (65536 + ((wcol << 6) + lm) * 64 + (ce8 << 1));   // B region

#define STAGE(kind, kh, tau) do {                                              \
        int taue_ = (tau) >= 16 ? (tau) - 2 : (tau);  /* dummy keeps vmcnt uniform */ \
        int ko_ = (taue_ << 6) + ((kh) << 5);                                  \
        unsigned lo_ = ((kind) << 16) + (((tau) & 1) << 15) + ((kh) << 14) + w1k; \
        const unsigned short* s_ = ((kind) ? srcB : srcA) + ko_;               \
        __builtin_amdgcn_global_load_lds(                                      \
            (const __attribute__((address_space(1))) void*)s_,                 \
            (__attribute__((address_space(3))) void*)(ldsc + lo_), 16, 0, 0);  \
        __builtin_amdgcn_global_load_lds(                                      \
            (const __attribute__((address_space(1))) void*)(s_ + rstep),       \
            (__attribute__((address_space(3))) void*)(ldsc + lo_ + 8192), 16, 0, 0); \
    } while (0)

#define MFMA4(R, AV)                                                           \
    do {                                                                       \
        acc[R][0] = __builtin_amdgcn_mfma_f32_16x16x32_bf16(AV, b4[0], acc[R][0], 0, 0, 0); \
        acc[R][1] = __builtin_amdgcn_mfma_f32_16x16x32_bf16(AV, b4[1], acc[R][1], 0, 0, 0); \
        acc[R][2] = __builtin_amdgcn_mfma_f32_16x16x32_bf16(AV, b4[2], acc[R][2], 0, 0, 0); \
        acc[R][3] = __builtin_amdgcn_mfma_f32_16x16x32_bf16(AV, b4[3], acc[R][3], 0, 0, 0); \
    } while (0)

    // prologue: tile0 {B0,A0,B1,A1} + tile1 {B0,A0,B1}
    STAGE(1, 0, 0); STAGE(0, 0, 0); STAGE(1, 1, 0); STAGE(0, 1, 0);
    STAGE(1, 0, 1); STAGE(0, 0, 1); STAGE(1, 1, 1);
    asm volatile("s_waitcnt vmcnt(6)" ::: "memory");
    SBAR();

    short8 na[4], b4[4];
    for (int t2 = 0; t2 < 16; t2 += 2) {
        #pragma unroll
        for (int s = 0; s < 8; s++) {
            const int hi = s >> 2;          // tile parity within pair (t2 even)
            const int s4 = s & 3;
            const int ks = s4 >> 1, ih = s4 & 1;
            const int tc = t2 + hi;
            constexpr int DB = 32768, KH = 16384, FR = 1024;
            const int PB = hi * DB + ks * KH;   // compile-time per unrolled s
            // issue order matters for the rolling lgkm counts: B first.
            if (s4 == 0 || s4 == 2) {
                DSR(b4[0], vb, PB + 0 * FR);
                DSR(b4[1], vb, PB + 1 * FR);
                DSR(b4[2], vb, PB + 2 * FR);
                DSR(b4[3], vb, PB + 3 * FR);
            }
            DSR(na[0], va, PB + (ih * 4 + 0) * FR);
            DSR(na[1], va, PB + (ih * 4 + 1) * FR);
            DSR(na[2], va, PB + (ih * 4 + 2) * FR);
            DSR(na[3], va, PB + (ih * 4 + 3) * FR);
            if      (s4 == 0) STAGE(0, 1, tc + 1);
            else if (s4 == 1) STAGE(1, 0, tc + 2);
            else if (s4 == 2) STAGE(0, 0, tc + 2);
            else              STAGE(1, 1, tc + 2);
            __builtin_amdgcn_s_setprio(1);
            // rolling waits: with B-phase (8 issued) lgkm(3) = b4[0..3]+na[0];
            // without (4 issued) lgkm(3) = na[0]. Same literals both ways.
            LGKM(3); __builtin_amdgcn_sched_barrier(0);
            MFMA4(ih * 4 + 0, na[0]);
            LGKM(2); __builtin_amdgcn_sched_barrier(0);
            MFMA4(ih * 4 + 1, na[1]);
            LGKM(1); __builtin_amdgcn_sched_barrier(0);
            MFMA4(ih * 4 + 2, na[2]);
            LGKM(0); __builtin_amdgcn_sched_barrier(0);
            MFMA4(ih * 4 + 3, na[3]);
            __builtin_amdgcn_s_setprio(0);
            if (s4 == 3) asm volatile("s_waitcnt vmcnt(6)" ::: "memory");
            SBAR();
        }
    }
#undef STAGE
#undef MFMA4
}

// ---- 256x256 tile store via LDS (two 128-row passes, stride 264) -----------
// Scattered 2B epilogue stores trigger L2 write-allocate HBM fetches; staging
// in LDS then streaming full 256B-per-row lines avoids it (verified lineage).
// First __syncthreads drains the in-flight dummy global_load_lds (full drain).
__device__ __forceinline__ void tile_store256(unsigned short* sm, // >= 128*264
                                              floatx4 (&acc)[8][4], float scale, int trans,
                                              unsigned short* __restrict__ C, int ldc,
                                              int rbase, int cbase)
{
    const int t = threadIdx.x, wave = t >> 6, lane = t & 63;
    const int wrow = wave >> 2, wcol = wave & 3;
    const int lm = lane & 15, rq = ((lane >> 4) << 2);
    #pragma unroll
    for (int h = 0; h < 2; h++) {
        __syncthreads();
        if (!trans) {
            if (wrow == h) {
                #pragma unroll
                for (int i = 0; i < 8; i++)
                    #pragma unroll
                    for (int j = 0; j < 4; j++)
                        #pragma unroll
                        for (int r = 0; r < 4; r++)
                            sm[(i * 16 + rq + r) * 264 + wcol * 64 + j * 16 + lm] =
                                f2bf(acc[i][j][r] * scale);
            }
        } else {
            if ((wcol >> 1) == h) {
                #pragma unroll
                for (int i = 0; i < 8; i++)
                    #pragma unroll
                    for (int j = 0; j < 4; j++) {
                        ushort4 v;
                        v.x = f2bf(acc[i][j][0] * scale);
                        v.y = f2bf(acc[i][j][1] * scale);
                        v.z = f2bf(acc[i][j][2] * scale);
                        v.w = f2bf(acc[i][j][3] * scale);
                        *(ushort4*)&sm[((wcol & 1) * 64 + j * 16 + lm) * 264 +
                                       wrow * 128 + i * 16 + rq] = v;
                    }
            }
        }
        __syncthreads();
        #pragma unroll
        for (int p = 0; p < 4; p++) {
            int row = p * 32 + (t >> 4);
            int c0  = (t & 15) * 8;
            *(short8*)&C[(size_t)(rbase + h * 128 + row) * ldc + cbase + c0] =
                *(const short8*)&sm[row * 264 + c0];
            *(short8*)&C[(size_t)(rbase + h * 128 + row) * ldc + cbase + c0 + 128] =
                *(const short8*)&sm[row * 264 + c0 + 128];
        }
    }
}

// ---- fused 3-way projection: {Wq->q(*1/32), Wk->k, Wv->vT} ----------------
struct P3 { const unsigned short* W[3]; unsigned short* O[3]; };
__global__ __launch_bounds__(512, 2)
void proj3(const unsigned short* __restrict__ xb, P3 a) {
    __shared__ __align__(16) unsigned short lds[65536];
    const int lid = blockIdx.x;                 // 0..191
    const int xcd = lid & 7, rem = lid >> 3;
    const int z   = rem >> 3;                   // 0..2
    const int idx = xcd * 8 + (rem & 7);        // 0..63
    const int by = idx >> 2, bx = idx & 3;      // 16 x 4 tiles of 256
    const int bm = by * 256, bn = bx * 256;

    floatx4 acc[8][4];
    #pragma unroll
    for (int i = 0; i < 8; i++)
        #pragma unroll
        for (int j = 0; j < 4; j++) { floatx4 zz = {0.f,0.f,0.f,0.f}; acc[i][j] = zz; }

    gemm256_core(xb, a.W[z], 1024, 0, bm, bn, lds, acc);

    const int trans = (z == 2);
    const float scale = (z == 0) ? 0.03125f : 1.0f;
    tile_store256(lds, acc, scale, trans, a.O[z],
                  trans ? 4096 : 1024, trans ? bn : bm, trans ? bm : bn);
}

// ---- PS-GEMM: P = exp(q k^T) bf16 (scale pre-folded into q), row sums -> l -
__global__ __launch_bounds__(512, 2)
void gemm_ps(const unsigned short* __restrict__ q, const unsigned short* __restrict__ k,
             unsigned short* __restrict__ Pm, float* __restrict__ l) {
    __shared__ __align__(16) unsigned short lds[65536];
    const int lid = blockIdx.x;                 // 0..255 (exactly 1 block/CU)
    const int xcd = lid & 7, r32 = lid >> 3;
    const int by = ((xcd >> 1) << 2) + (r32 & 3);
    const int bx = ((xcd & 1) << 3) + (r32 >> 2);
    const int bm = by * 256, bn = bx * 256;

    floatx4 acc[8][4];
    #pragma unroll
    for (int i = 0; i < 8; i++)
        #pragma unroll
        for (int j = 0; j < 4; j++) { floatx4 zz = {0.f,0.f,0.f,0.f}; acc[i][j] = zz; }

    gemm256_core(q, k, 1024, 0, bm, bn, lds, acc);

    const int lane = threadIdx.x & 63, wave = threadIdx.x >> 6;
    const int wrow = wave >> 2;
    const int lm = lane & 15, rq = ((lane >> 4) << 2);
    #pragma unroll
    for (int i = 0; i < 8; i++) {
        #pragma unroll
        for (int r = 0; r < 4; r++) {
            float rs = 0.f;
            #pragma unroll
            for (int j = 0; j < 4; j++) {
                float e = __expf(acc[i][j][r]);
                acc[i][j][r] = e;
                rs += e;
            }
            rs += __shfl_xor(rs, 1);
            rs += __shfl_xor(rs, 2);
            rs += __shfl_xor(rs, 4);
            rs += __shfl_xor(rs, 8);
            if (lm == 0) atomicAdd(l + bm + wrow * 128 + i * 16 + rq + r, rs);
        }
    }
    tile_store256(lds, acc, 1.0f, 0, Pm, 4096, bm, bn);
}

// ---- O-GEMM split-K=4: 256x256 tiles, bf16 partials ------------------------
__global__ __launch_bounds__(512, 2)
void gemm_osplit(const unsigned short* __restrict__ Pm, const unsigned short* __restrict__ vT,
                 unsigned short* __restrict__ Opart) {
    __shared__ __align__(16) unsigned short lds[65536];
    const int lid = blockIdx.x;                 // 0..255
    const int xcd = lid & 7, r32 = lid >> 3;
    const int z   = r32 & 3;                    // K quarter
    const int idx = (r32 >> 2) * 8 + xcd;       // 0..63
    const int by = idx >> 2, bx = idx & 3;      // 16 x 4 tiles

    floatx4 acc[8][4];
    #pragma unroll
    for (int i = 0; i < 8; i++)
        #pragma unroll
        for (int j = 0; j < 4; j++) { floatx4 zz = {0.f,0.f,0.f,0.f}; acc[i][j] = zz; }

    gemm256_core(Pm, vT, 4096, z * 1024, by * 256, bx * 256, lds, acc);

    tile_store256(lds, acc, 1.0f, 0, Opart + (size_t)z * (4096 * 1024), 1024,
                  by * 256, bx * 256);
}

// ---- reduce 4 bf16 split-K partials + apply deferred 1/l row scale ---------
__global__ __launch_bounds__(256)
void reduce_scale(const unsigned short* __restrict__ Op, const float* __restrict__ l,
                  float* __restrict__ out) {
    int i = (blockIdx.x * 256 + threadIdx.x) * 4;
    ushort4 a = *(const ushort4*)(Op + i);
    ushort4 b = *(const ushort4*)(Op + 4194304 + i);
    ushort4 c = *(const ushort4*)(Op + 8388608 + i);
    ushort4 d = *(const ushort4*)(Op + 12582912 + i);
    float inv = 1.0f / l[i >> 10];
    float4 o;
    o.x = (bf2f(a.x) + bf2f(b.x) + bf2f(c.x) + bf2f(d.x)) * inv;
    o.y = (bf2f(a.y) + bf2f(b.y) + bf2f(c.y) + bf2f(d.y)) * inv;
    o.z = (bf2f(a.z) + bf2f(b.z) + bf2f(c.z) + bf2f(d.z)) * inv;
    o.w = (bf2f(a.w) + bf2f(b.w) + bf2f(c.w) + bf2f(d.w)) * inv;
    *(float4*)(out + i) = o;
}

// ---------------- driver -----------------------------------------------
extern "C" void kernel_launch(void* const* d_in, const int* in_sizes, int n_in,
                              void* d_out, int out_size, void* d_ws, size_t ws_size,
                              hipStream_t stream) {
    const float* x  = (const float*)d_in[0];
    const float* Wq = (const float*)d_in[1];
    const float* Wk = (const float*)d_in[2];
    const float* Wv = (const float*)d_in[3];
    float* out = (float*)d_out;

    char* ws = (char*)d_ws;
    const size_t MB = 1u << 20;
    unsigned short* vTb = (unsigned short*)(ws);             //  0..8   bf16 [D x SEQ]
    unsigned short* xb  = (unsigned short*)(ws + 8 * MB);    //  8..16
    unsigned short* Wqb = (unsigned short*)(ws + 16 * MB);   // 16..18
    unsigned short* Wkb = (unsigned short*)(ws + 18 * MB);   // 18..20
    unsigned short* Wvb = (unsigned short*)(ws + 20 * MB);   // 20..22
    unsigned short* qb  = (unsigned short*)(ws + 22 * MB);   // 22..30
    unsigned short* kb  = (unsigned short*)(ws + 30 * MB);   // 30..38
    unsigned short* P   = (unsigned short*)(ws + 40 * MB);   // 40..72  bf16 [SEQ x SEQ]
    float*          l   = (float*)(ws + 72 * MB);            // 72..72.016 row sums
    // Opart aliases xb/W/qb/kb (all dead once gemm_ps has run): 4 x 8 MB
    unsigned short* Opart = (unsigned short*)(ws + 8 * MB);  //  8..40

    dim3 b256(256), b512(512);
    CV cv = {x, xb, {Wq, Wk, Wv}, {Wqb, Wkb, Wvb}, l};
    cvt_all<<<dim3(3585), b256, 0, stream>>>(cv);

    // q(*1/32)/k/vT: 256x256 tiles, 8-phase core, 192 blocks
    P3 p3 = {{Wqb, Wkb, Wvb}, {qb, kb, vTb}};
    proj3<<<dim3(192), b512, 0, stream>>>(xb, p3);

    // P = exp(q k^T) bf16 + row sums l (256 blocks = 1/CU)
    gemm_ps<<<dim3(256), b512, 0, stream>>>(qb, kb, P, l);

    // O partials bf16, split-K=4 (256 blocks)
    gemm_osplit<<<dim3(256), b512, 0, stream>>>(P, vTb, Opart);

    // out = (sum of 4 partials) / l[row]
    reduce_scale<<<dim3(4096), b256, 0, stream>>>(Opart, l, out);
}